// Round 1
// baseline (109.004 us; speedup 1.0000x reference)
//
#include <hip/hip_runtime.h>

#define NN 8192
#define DD 128
#define CH 16           // column chunks
#define CPC (NN / CH)   // cols per chunk = 512
#define TILES (CPC / 64)
#define NPART 64        // partial-sum bins

typedef __bf16 bf16x8 __attribute__((ext_vector_type(8)));
typedef float f32x4 __attribute__((ext_vector_type(4)));

#define PACK_INIT __uint_as_float(0x7F7FFFFFu)

// Pack (score, idx): high 19 bits of fp32 score, idx in low 13 (round 5-10,
// absmax 0.0 throughout).
static __device__ __forceinline__ float packsi(float s, unsigned idx) {
  return __uint_as_float((__float_as_uint(s) & 0xFFFFE000u) | idx);
}

// Sorted-insert via med3: closed form sk' = med3(v, s[k-1], sk), s0' = min.
// 5 ops (NET5) / 4 ops (NET4), dependency depth 1 (vs 9/7 ops depth 5 of the
// min/max network) — v_med3_f32 is full-rate VOP3.
#define NET4(S0, S1, S2, S3, v)                                                \
  {                                                                            \
    float v_ = (v), o0 = S0, o1 = S1, o2 = S2;                                 \
    S0 = fminf(o0, v_);                                                        \
    S1 = __builtin_amdgcn_fmed3f(v_, o0, o1);                                  \
    S2 = __builtin_amdgcn_fmed3f(v_, o1, o2);                                  \
    S3 = __builtin_amdgcn_fmed3f(v_, o2, S3);                                  \
  }
#define NET5(S0, S1, S2, S3, S4, v)                                            \
  {                                                                            \
    float v_ = (v), o0 = S0, o1 = S1, o2 = S2, o3 = S3;                        \
    S0 = fminf(o0, v_);                                                        \
    S1 = __builtin_amdgcn_fmed3f(v_, o0, o1);                                  \
    S2 = __builtin_amdgcn_fmed3f(v_, o1, o2);                                  \
    S3 = __builtin_amdgcn_fmed3f(v_, o2, o3);                                  \
    S4 = __builtin_amdgcn_fmed3f(v_, o3, S4);                                  \
  }

static __device__ __forceinline__ unsigned short f2bf(float f) {
  unsigned u = __float_as_uint(f);
  u += 0x7FFFu + ((u >> 16) & 1u);   // round-to-nearest-even
  return (unsigned short)(u >> 16);
}

// Kernel 1: f32->bf16 convert, fp32 row sq-norms, zero partial bins.
__global__ __launch_bounds__(256) void prep_kernel(const float* __restrict__ x,
                                                   unsigned short* __restrict__ xb,
                                                   float* __restrict__ sq,
                                                   float* __restrict__ partial) {
  const int wave = threadIdx.x >> 6, lane = threadIdx.x & 63;
  const int row = blockIdx.x * 4 + wave;
  const float2 v = ((const float2*)(x + (size_t)row * DD))[lane];
  float ss = v.x * v.x + v.y * v.y;
#pragma unroll
  for (int off = 32; off; off >>= 1) ss += __shfl_down(ss, off);
  if (lane == 0) sq[row] = ss;
  unsigned packed = (unsigned)f2bf(v.x) | ((unsigned)f2bf(v.y) << 16);
  ((unsigned*)(xb + (size_t)row * DD))[lane] = packed;
  if (blockIdx.x == 0 && threadIdx.x < NPART) partial[threadIdx.x] = 0.0f;
}

// Kernel 2: LDS-staged bf16-MFMA scores + med3 packed top-k.
// 64 rows/wave (4 row-groups of 16 share every B fragment). Block = 256 rows
// x 512 cols; grid (32,16) = 512 blocks = 2/CU. Off-diagonal blocks keep
// top-4 (self absent); diagonal blocks (bx>>1==by) keep top-5.
__global__ __launch_bounds__(256, 2) void dist_topk_kernel(
    const unsigned short* __restrict__ xb, const float* __restrict__ sq,
    float* __restrict__ pscore) {
  const int t = threadIdx.x;
  const int wave = t >> 6, lane = t & 63;
  const int lrow = lane & 15, lquad = lane >> 4;
  const int rowBase = blockIdx.x * 256;
  const int chunk = blockIdx.y;
  const int j0 = chunk * CPC;
  const bool hasDiag = ((blockIdx.x >> 1) == (int)blockIdx.y);

  __shared__ unsigned short colsB[2][64 * DD];   // 2 x 16 KB, XOR-swizzled
  __shared__ float sqs[2][64];

  // A fragments for 4 row-groups: lane holds X[row][k=lquad*8+j].
  const int r0 = rowBase + wave * 64 + lrow;     // group g row = r0 + g*16
  const unsigned short* ap0 = xb + (size_t)(r0)*DD + lquad * 8;
  const unsigned short* ap1 = xb + (size_t)(r0 + 16) * DD + lquad * 8;
  const unsigned short* ap2 = xb + (size_t)(r0 + 32) * DD + lquad * 8;
  const unsigned short* ap3 = xb + (size_t)(r0 + 48) * DD + lquad * 8;
  bf16x8 a00 = *(const bf16x8*)(ap0), a01 = *(const bf16x8*)(ap0 + 32),
         a02 = *(const bf16x8*)(ap0 + 64), a03 = *(const bf16x8*)(ap0 + 96);
  bf16x8 a10 = *(const bf16x8*)(ap1), a11 = *(const bf16x8*)(ap1 + 32),
         a12 = *(const bf16x8*)(ap1 + 64), a13 = *(const bf16x8*)(ap1 + 96);
  bf16x8 a20 = *(const bf16x8*)(ap2), a21 = *(const bf16x8*)(ap2 + 32),
         a22 = *(const bf16x8*)(ap2 + 64), a23 = *(const bf16x8*)(ap2 + 96);
  bf16x8 a30 = *(const bf16x8*)(ap3), a31 = *(const bf16x8*)(ap3 + 32),
         a32 = *(const bf16x8*)(ap3 + 64), a33 = *(const bf16x8*)(ap3 + 96);

  // Packed sorted lists, one per row-group, named scalars.
  float q00 = PACK_INIT, q01 = PACK_INIT, q02 = PACK_INIT, q03 = PACK_INIT,
        q04 = PACK_INIT;
  float q10 = PACK_INIT, q11 = PACK_INIT, q12 = PACK_INIT, q13 = PACK_INIT,
        q14 = PACK_INIT;
  float q20 = PACK_INIT, q21 = PACK_INIT, q22 = PACK_INIT, q23 = PACK_INIT,
        q24 = PACK_INIT;
  float q30 = PACK_INIT, q31 = PACK_INIT, q32 = PACK_INIT, q33 = PACK_INIT,
        q34 = PACK_INIT;

  // Staging closed-form swizzle (round-5 verified).
  const int sr = t >> 4, sch = t & 15;
  const int dst0 = (sr << 4) | (sch ^ (sr & 15));

  const float4* srcv = (const float4*)(xb + (size_t)j0 * DD);
  float4 g0 = srcv[t], g1 = srcv[t + 256], g2 = srcv[t + 512], g3 = srcv[t + 768];
  float sqv = 0.0f;
  if (t < 64) sqv = sq[j0 + t];

#define KBODY(INSROW)                                                          \
  for (int it = 0; it < TILES; ++it) {                                         \
    const int jt = j0 + it * 64;                                               \
    const int cur = it & 1;                                                    \
    {                                                                          \
      float4* dstv = (float4*)colsB[cur];                                      \
      dstv[dst0] = g0;                                                         \
      dstv[dst0 + 256] = g1;                                                   \
      dstv[dst0 + 512] = g2;                                                   \
      dstv[dst0 + 768] = g3;                                                   \
      if (t < 64) sqs[cur][t] = sqv;                                           \
    }                                                                          \
    if (it + 1 < TILES) {                                                      \
      const float4* nsrc = (const float4*)(xb + (size_t)(jt + 64) * DD);       \
      g0 = nsrc[t]; g1 = nsrc[t + 256]; g2 = nsrc[t + 512]; g3 = nsrc[t + 768];\
      if (t < 64) sqv = sq[jt + 64 + t];                                       \
    }                                                                          \
    __syncthreads();                                                           \
    _Pragma("unroll")                                                          \
    for (int ct = 0; ct < 4; ++ct) {                                           \
      const unsigned short* bb = &colsB[cur][(ct * 16 + lrow) * DD];           \
      bf16x8 b0 = *(const bf16x8*)(bb + (((0 + lquad) ^ lrow) << 3));          \
      bf16x8 b1 = *(const bf16x8*)(bb + (((4 + lquad) ^ lrow) << 3));          \
      bf16x8 b2 = *(const bf16x8*)(bb + (((8 + lquad) ^ lrow) << 3));          \
      bf16x8 b3 = *(const bf16x8*)(bb + (((12 + lquad) ^ lrow) << 3));         \
      f32x4 ac0 = {0.f, 0.f, 0.f, 0.f}, ac1 = {0.f, 0.f, 0.f, 0.f};           \
      f32x4 ac2 = {0.f, 0.f, 0.f, 0.f}, ac3 = {0.f, 0.f, 0.f, 0.f};           \
      ac0 = __builtin_amdgcn_mfma_f32_16x16x32_bf16(b0, a00, ac0, 0, 0, 0);    \
      ac1 = __builtin_amdgcn_mfma_f32_16x16x32_bf16(b0, a10, ac1, 0, 0, 0);    \
      ac2 = __builtin_amdgcn_mfma_f32_16x16x32_bf16(b0, a20, ac2, 0, 0, 0);    \
      ac3 = __builtin_amdgcn_mfma_f32_16x16x32_bf16(b0, a30, ac3, 0, 0, 0);    \
      ac0 = __builtin_amdgcn_mfma_f32_16x16x32_bf16(b1, a01, ac0, 0, 0, 0);    \
      ac1 = __builtin_amdgcn_mfma_f32_16x16x32_bf16(b1, a11, ac1, 0, 0, 0);    \
      ac2 = __builtin_amdgcn_mfma_f32_16x16x32_bf16(b1, a21, ac2, 0, 0, 0);    \
      ac3 = __builtin_amdgcn_mfma_f32_16x16x32_bf16(b1, a31, ac3, 0, 0, 0);    \
      ac0 = __builtin_amdgcn_mfma_f32_16x16x32_bf16(b2, a02, ac0, 0, 0, 0);    \
      ac1 = __builtin_amdgcn_mfma_f32_16x16x32_bf16(b2, a12, ac1, 0, 0, 0);    \
      ac2 = __builtin_amdgcn_mfma_f32_16x16x32_bf16(b2, a22, ac2, 0, 0, 0);    \
      ac3 = __builtin_amdgcn_mfma_f32_16x16x32_bf16(b2, a32, ac3, 0, 0, 0);    \
      ac0 = __builtin_amdgcn_mfma_f32_16x16x32_bf16(b3, a03, ac0, 0, 0, 0);    \
      ac1 = __builtin_amdgcn_mfma_f32_16x16x32_bf16(b3, a13, ac1, 0, 0, 0);    \
      ac2 = __builtin_amdgcn_mfma_f32_16x16x32_bf16(b3, a23, ac2, 0, 0, 0);    \
      ac3 = __builtin_amdgcn_mfma_f32_16x16x32_bf16(b3, a33, ac3, 0, 0, 0);    \
      const f32x4 sq4 = *(const f32x4*)&sqs[cur][ct * 16 + lquad * 4];         \
      const unsigned colb = (unsigned)(jt + ct * 16 + lquad * 4);              \
      _Pragma("unroll")                                                        \
      for (int r = 0; r < 4; ++r) {                                            \
        INSROW(0, packsi(fmaf(-2.0f, ac0[r], sq4[r]), colb + r));              \
        INSROW(1, packsi(fmaf(-2.0f, ac1[r], sq4[r]), colb + r));              \
        INSROW(2, packsi(fmaf(-2.0f, ac2[r], sq4[r]), colb + r));              \
        INSROW(3, packsi(fmaf(-2.0f, ac3[r], sq4[r]), colb + r));              \
      }                                                                        \
    }                                                                          \
  }

#define INS4(G, V) NET4(q##G##0, q##G##1, q##G##2, q##G##3, (V))
#define INS5(G, V) NET5(q##G##0, q##G##1, q##G##2, q##G##3, q##G##4, (V))

  if (hasDiag) {
    KBODY(INS5)
  } else {
    KBODY(INS4)
  }
#undef KBODY

  // Merge across lquads (lanes sharing lrow hold the same 4 rows).
#define MERGE4(G, M)                                                           \
  {                                                                            \
    float o0 = __shfl_xor(q##G##0, M), o1 = __shfl_xor(q##G##1, M),            \
          o2 = __shfl_xor(q##G##2, M), o3 = __shfl_xor(q##G##3, M);            \
    NET4(q##G##0, q##G##1, q##G##2, q##G##3, o0);                              \
    NET4(q##G##0, q##G##1, q##G##2, q##G##3, o1);                              \
    NET4(q##G##0, q##G##1, q##G##2, q##G##3, o2);                              \
    NET4(q##G##0, q##G##1, q##G##2, q##G##3, o3);                              \
  }
#define MERGE5(G, M)                                                           \
  {                                                                            \
    float o0 = __shfl_xor(q##G##0, M), o1 = __shfl_xor(q##G##1, M),            \
          o2 = __shfl_xor(q##G##2, M), o3 = __shfl_xor(q##G##3, M),            \
          o4 = __shfl_xor(q##G##4, M);                                         \
    NET5(q##G##0, q##G##1, q##G##2, q##G##3, q##G##4, o0);                     \
    NET5(q##G##0, q##G##1, q##G##2, q##G##3, q##G##4, o1);                     \
    NET5(q##G##0, q##G##1, q##G##2, q##G##3, q##G##4, o2);                     \
    NET5(q##G##0, q##G##1, q##G##2, q##G##3, q##G##4, o3);                     \
    NET5(q##G##0, q##G##1, q##G##2, q##G##3, q##G##4, o4);                     \
  }
  if (hasDiag) {
    MERGE5(0, 16) MERGE5(1, 16) MERGE5(2, 16) MERGE5(3, 16)
    MERGE5(0, 32) MERGE5(1, 32) MERGE5(2, 32) MERGE5(3, 32)
  } else {
    MERGE4(0, 16) MERGE4(1, 16) MERGE4(2, 16) MERGE4(3, 16)
    MERGE4(0, 32) MERGE4(1, 32) MERGE4(2, 32) MERGE4(3, 32)
  }

  if (lquad == 0) {
    // pscore layout: [row][CH*5] -> coalesced per-row read in final_kernel.
    float* b0p = pscore + (size_t)(r0)*80 + chunk * 5;
    b0p[0] = q00; b0p[1] = q01; b0p[2] = q02; b0p[3] = q03; b0p[4] = q04;
    float* b1p = pscore + (size_t)(r0 + 16) * 80 + chunk * 5;
    b1p[0] = q10; b1p[1] = q11; b1p[2] = q12; b1p[3] = q13; b1p[4] = q14;
    float* b2p = pscore + (size_t)(r0 + 32) * 80 + chunk * 5;
    b2p[0] = q20; b2p[1] = q21; b2p[2] = q22; b2p[3] = q23; b2p[4] = q24;
    float* b3p = pscore + (size_t)(r0 + 48) * 80 + chunk * 5;
    b3p[0] = q30; b3p[1] = q31; b3p[2] = q32; b3p[3] = q33; b3p[4] = q34;
  }
}

// Kernel 3: chunk merge (packed) -> neg idx -> exact fp32 hinge -> 64 bins
// (round-6 lesson in reverse: 2048 same-address atomics cost ~10 us; bins
// parallelize the serialization).
__global__ __launch_bounds__(256) void final_kernel(const float* __restrict__ x,
                                                    const float* __restrict__ pos,
                                                    const float* __restrict__ pscore,
                                                    float* __restrict__ partial) {
  const int wave = threadIdx.x >> 6, lane = threadIdx.x & 63;
  const int row = blockIdx.x * 4 + wave;

  float q0 = PACK_INIT, q1 = PACK_INIT, q2 = PACK_INIT, q3 = PACK_INIT,
        q4 = PACK_INIT;
  if (lane < CH) {
    const float* b = pscore + (size_t)row * 80 + lane * 5;   // contiguous row
    q0 = b[0]; q1 = b[1]; q2 = b[2]; q3 = b[3]; q4 = b[4];
  }
#pragma unroll
  for (int m = 1; m < CH; m <<= 1) {
    float o0 = __shfl_xor(q0, m), o1 = __shfl_xor(q1, m), o2 = __shfl_xor(q2, m),
          o3 = __shfl_xor(q3, m), o4 = __shfl_xor(q4, m);
    NET5(q0, q1, q2, q3, q4, o0);
    NET5(q0, q1, q2, q3, q4, o1);
    NET5(q0, q1, q2, q3, q4, o2);
    NET5(q0, q1, q2, q3, q4, o3);
    NET5(q0, q1, q2, q3, q4, o4);
  }
  const int nidx = (int)(__float_as_uint(__shfl(q4, 0)) & 0x1FFFu);

  const float2 xv  = ((const float2*)(x   + (size_t)row  * DD))[lane];
  const float2 pv  = ((const float2*)(pos + (size_t)row  * DD))[lane];
  const float2 nvv = ((const float2*)(x   + (size_t)nidx * DD))[lane];
  float a0 = xv.x - pv.x + 1e-6f, a1 = xv.y - pv.y + 1e-6f;
  float b0 = xv.x - nvv.x + 1e-6f, b1 = xv.y - nvv.y + 1e-6f;
  float dap = a0 * a0 + a1 * a1;
  float dan = b0 * b0 + b1 * b1;
#pragma unroll
  for (int off = 32; off; off >>= 1) {
    dap += __shfl_down(dap, off);
    dan += __shfl_down(dan, off);
  }
  __shared__ float hs[4];
  if (lane == 0) hs[wave] = fmaxf(sqrtf(dap) - sqrtf(dan) + 0.3f, 0.0f);
  __syncthreads();
  if (threadIdx.x == 0) {
    float s = hs[0] + hs[1] + hs[2] + hs[3];
    atomicAdd(&partial[blockIdx.x & (NPART - 1)], s);
  }
}

// Kernel 4: one wave sums the 64 bins -> mean.
__global__ __launch_bounds__(64) void reduce_kernel(const float* __restrict__ partial,
                                                    float* __restrict__ out) {
  float v = partial[threadIdx.x];
#pragma unroll
  for (int off = 32; off; off >>= 1) v += __shfl_down(v, off);
  if (threadIdx.x == 0) out[0] = v * (1.0f / 8192.0f);
}

extern "C" void kernel_launch(void* const* d_in, const int* in_sizes, int n_in,
                              void* d_out, int out_size, void* d_ws, size_t ws_size,
                              hipStream_t stream) {
  const float* x   = (const float*)d_in[0];
  const float* pos = (const float*)d_in[1];
  float* out = (float*)d_out;

  char* w = (char*)d_ws;
  unsigned short* xb = (unsigned short*)w;                       // 2 MB
  float* sq = (float*)(w + (size_t)NN * DD * 2);                 // 32 KB
  float* pscore = (float*)(w + (size_t)NN * DD * 2 + (size_t)NN * 4);  // 2.62 MB
  float* partial = (float*)(w + (size_t)NN * DD * 2 + (size_t)NN * 4 +
                            (size_t)NN * 80 * 4);                // 256 B

  prep_kernel<<<NN / 4, 256, 0, stream>>>(x, xb, sq, partial);
  dist_topk_kernel<<<dim3(NN / 256, CH), 256, 0, stream>>>(xb, sq, pscore);
  final_kernel<<<NN / 4, 256, 0, stream>>>(x, pos, pscore, partial);
  reduce_kernel<<<1, 64, 0, stream>>>(partial, out);
}

// Round 2
// 103.881 us; speedup vs baseline: 1.0493x; 1.0493x over previous
//
#include <hip/hip_runtime.h>

#define NN 8192
#define DD 128
#define CH 16           // column chunks
#define CPC (NN / CH)   // cols per chunk = 512
#define TILES (CPC / 64)
#define NPART 64        // partial-sum bins

typedef __bf16 bf16x8 __attribute__((ext_vector_type(8)));
typedef float f32x4 __attribute__((ext_vector_type(4)));

// Max-network init: most negative finite float (all scores are < 0 by the -70 bias).
#define PACK_INIT __uint_as_float(0xFF7FFFFFu)

// Pack (score, idx): high 19 bits of fp32 score, idx in low 13. Scores are
// always NEGATIVE (score = dot - 0.5*sq_col - 70), so under fmaxf a larger idx
// makes the float more negative -> ties prefer the SMALLER idx (matches top_k).
static __device__ __forceinline__ float packsi(float s, unsigned idx) {
  return __uint_as_float((__float_as_uint(s) & 0xFFFFE000u) | idx);
}

// Sorted-insert (DESCENDING list, keep top-k LARGEST) via med3:
// q0' = max(q0, v); qk' = med3(v, q[k-1], qk). Depth 1, full-rate VOP3.
#define NET4(S0, S1, S2, S3, v)                                                \
  {                                                                            \
    float v_ = (v), o0 = S0, o1 = S1, o2 = S2;                                 \
    S0 = fmaxf(o0, v_);                                                        \
    S1 = __builtin_amdgcn_fmed3f(v_, o0, o1);                                  \
    S2 = __builtin_amdgcn_fmed3f(v_, o1, o2);                                  \
    S3 = __builtin_amdgcn_fmed3f(v_, o2, S3);                                  \
  }
#define NET5(S0, S1, S2, S3, S4, v)                                            \
  {                                                                            \
    float v_ = (v), o0 = S0, o1 = S1, o2 = S2, o3 = S3;                        \
    S0 = fmaxf(o0, v_);                                                        \
    S1 = __builtin_amdgcn_fmed3f(v_, o0, o1);                                  \
    S2 = __builtin_amdgcn_fmed3f(v_, o1, o2);                                  \
    S3 = __builtin_amdgcn_fmed3f(v_, o2, o3);                                  \
    S4 = __builtin_amdgcn_fmed3f(v_, o3, S4);                                  \
  }

static __device__ __forceinline__ unsigned short f2bf(float f) {
  unsigned u = __float_as_uint(f);
  u += 0x7FFFu + ((u >> 16) & 1u);   // round-to-nearest-even
  return (unsigned short)(u >> 16);
}

// width-16 global->LDS DMA (linear LDS dest = wave-uniform base + lane*16).
static __device__ __forceinline__ void gload_lds16(const void* g, void* l) {
  __builtin_amdgcn_global_load_lds(
      (const __attribute__((address_space(1))) unsigned*)g,
      (__attribute__((address_space(3))) unsigned*)l, 16, 0, 0);
}

// Kernel 1: f32->bf16 convert, staged col-score bias (-0.5*sq - 70), zero bins.
__global__ __launch_bounds__(256) void prep_kernel(const float* __restrict__ x,
                                                   unsigned short* __restrict__ xb,
                                                   float* __restrict__ sq,
                                                   float* __restrict__ partial) {
  const int wave = threadIdx.x >> 6, lane = threadIdx.x & 63;
  const int row = blockIdx.x * 4 + wave;
  const float2 v = ((const float2*)(x + (size_t)row * DD))[lane];
  float ss = v.x * v.x + v.y * v.y;
#pragma unroll
  for (int off = 32; off; off >>= 1) ss += __shfl_down(ss, off);
  if (lane == 0) sq[row] = fmaf(-0.5f, ss, -70.0f);   // C-init for MFMA epilogue
  unsigned packed = (unsigned)f2bf(v.x) | ((unsigned)f2bf(v.y) << 16);
  ((unsigned*)(xb + (size_t)row * DD))[lane] = packed;
  if (blockIdx.x == 0 && threadIdx.x < NPART) partial[threadIdx.x] = 0.0f;
}

// Kernel 2: bf16-MFMA scores (C preloaded with -0.5*sq_col-70 -> no epilogue
// fmaf) + med3 packed top-k (max networks). Staging via global_load_lds with
// pre-swizzled SOURCE + linear LDS dest (rule-21 combo); ds_read side keeps the
// verified XOR swizzle. 64 rows/wave; block 256 rows x 512 cols; grid (32,16).
__global__ __launch_bounds__(256, 2) void dist_topk_kernel(
    const unsigned short* __restrict__ xb, const float* __restrict__ sq,
    float* __restrict__ pscore) {
  const int t = threadIdx.x;
  const int wave = t >> 6, lane = t & 63;
  const int lrow = lane & 15, lquad = lane >> 4;
  const int rowBase = blockIdx.x * 256;
  const int chunk = blockIdx.y;
  const int j0 = chunk * CPC;
  const bool hasDiag = ((blockIdx.x >> 1) == (int)blockIdx.y);

  __shared__ unsigned short colsB[2][64 * DD];   // 2 x 16 KB, XOR-swizzled image
  __shared__ float sqs_all[CPC];                 // whole chunk's col bias, 2 KB

  // A fragments for 4 row-groups: lane holds X[row][k=lquad*8+j].
  const int r0 = rowBase + wave * 64 + lrow;     // group g row = r0 + g*16
  const unsigned short* ap0 = xb + (size_t)(r0)*DD + lquad * 8;
  const unsigned short* ap1 = xb + (size_t)(r0 + 16) * DD + lquad * 8;
  const unsigned short* ap2 = xb + (size_t)(r0 + 32) * DD + lquad * 8;
  const unsigned short* ap3 = xb + (size_t)(r0 + 48) * DD + lquad * 8;
  bf16x8 a00 = *(const bf16x8*)(ap0), a01 = *(const bf16x8*)(ap0 + 32),
         a02 = *(const bf16x8*)(ap0 + 64), a03 = *(const bf16x8*)(ap0 + 96);
  bf16x8 a10 = *(const bf16x8*)(ap1), a11 = *(const bf16x8*)(ap1 + 32),
         a12 = *(const bf16x8*)(ap1 + 64), a13 = *(const bf16x8*)(ap1 + 96);
  bf16x8 a20 = *(const bf16x8*)(ap2), a21 = *(const bf16x8*)(ap2 + 32),
         a22 = *(const bf16x8*)(ap2 + 64), a23 = *(const bf16x8*)(ap2 + 96);
  bf16x8 a30 = *(const bf16x8*)(ap3), a31 = *(const bf16x8*)(ap3 + 32),
         a32 = *(const bf16x8*)(ap3 + 64), a33 = *(const bf16x8*)(ap3 + 96);

  // Packed sorted lists (descending), one per row-group.
  float q00 = PACK_INIT, q01 = PACK_INIT, q02 = PACK_INIT, q03 = PACK_INIT,
        q04 = PACK_INIT;
  float q10 = PACK_INIT, q11 = PACK_INIT, q12 = PACK_INIT, q13 = PACK_INIT,
        q14 = PACK_INIT;
  float q20 = PACK_INIT, q21 = PACK_INIT, q22 = PACK_INIT, q23 = PACK_INIT,
        q24 = PACK_INIT;
  float q30 = PACK_INIT, q31 = PACK_INIT, q32 = PACK_INIT, q33 = PACK_INIT,
        q34 = PACK_INIT;

  // DMA source pre-swizzle: LDS[i] = src[p(i)] with the involution
  // p(i) = (i & ~15) | ((i&15) ^ ((i>>4)&15)); identical image to the old
  // reg-staged LDS[p(t)] = src[t] store (p is an involution, p(i+256k)=p(i)+256k).
  const int psl = (t & ~15) | ((t ^ (t >> 4)) & 15);

#define ISSUE_TILE(buf, jtrow)                                                 \
  {                                                                            \
    const float4* s_ = (const float4*)(xb + (size_t)(jtrow)*DD);               \
    char* l_ = (char*)(&colsB[buf][0]) + wave * 1024;                          \
    gload_lds16(s_ + psl, l_);                                                 \
    gload_lds16(s_ + psl + 256, l_ + 4096);                                    \
    gload_lds16(s_ + psl + 512, l_ + 8192);                                    \
    gload_lds16(s_ + psl + 768, l_ + 12288);                                   \
  }

  // Prologue: stage whole-chunk col bias + DMA tile 0.
  sqs_all[t] = sq[j0 + t];
  sqs_all[t + 256] = sq[j0 + 256 + t];
  ISSUE_TILE(0, j0)

#define KBODY(INSROW)                                                          \
  for (int it = 0; it < TILES; ++it) {                                         \
    const int jt = j0 + it * 64;                                               \
    const int cur = it & 1;                                                    \
    __syncthreads(); /* drains this tile's DMA (vmcnt) + LDS writes */         \
    if (it + 1 < TILES) { ISSUE_TILE(cur ^ 1, jt + 64) }                       \
    _Pragma("unroll")                                                          \
    for (int ct = 0; ct < 4; ++ct) {                                           \
      const unsigned short* bb = &colsB[cur][(ct * 16 + lrow) * DD];           \
      bf16x8 b0 = *(const bf16x8*)(bb + (((0 + lquad) ^ lrow) << 3));          \
      bf16x8 b1 = *(const bf16x8*)(bb + (((4 + lquad) ^ lrow) << 3));          \
      bf16x8 b2 = *(const bf16x8*)(bb + (((8 + lquad) ^ lrow) << 3));          \
      bf16x8 b3 = *(const bf16x8*)(bb + (((12 + lquad) ^ lrow) << 3));         \
      const f32x4 nsq4 = *(const f32x4*)&sqs_all[it * 64 + ct * 16 + lquad * 4];\
      f32x4 ac0 = __builtin_amdgcn_mfma_f32_16x16x32_bf16(b0, a00, nsq4, 0, 0, 0);\
      f32x4 ac1 = __builtin_amdgcn_mfma_f32_16x16x32_bf16(b0, a10, nsq4, 0, 0, 0);\
      f32x4 ac2 = __builtin_amdgcn_mfma_f32_16x16x32_bf16(b0, a20, nsq4, 0, 0, 0);\
      f32x4 ac3 = __builtin_amdgcn_mfma_f32_16x16x32_bf16(b0, a30, nsq4, 0, 0, 0);\
      ac0 = __builtin_amdgcn_mfma_f32_16x16x32_bf16(b1, a01, ac0, 0, 0, 0);    \
      ac1 = __builtin_amdgcn_mfma_f32_16x16x32_bf16(b1, a11, ac1, 0, 0, 0);    \
      ac2 = __builtin_amdgcn_mfma_f32_16x16x32_bf16(b1, a21, ac2, 0, 0, 0);    \
      ac3 = __builtin_amdgcn_mfma_f32_16x16x32_bf16(b1, a31, ac3, 0, 0, 0);    \
      ac0 = __builtin_amdgcn_mfma_f32_16x16x32_bf16(b2, a02, ac0, 0, 0, 0);    \
      ac1 = __builtin_amdgcn_mfma_f32_16x16x32_bf16(b2, a12, ac1, 0, 0, 0);    \
      ac2 = __builtin_amdgcn_mfma_f32_16x16x32_bf16(b2, a22, ac2, 0, 0, 0);    \
      ac3 = __builtin_amdgcn_mfma_f32_16x16x32_bf16(b2, a32, ac3, 0, 0, 0);    \
      ac0 = __builtin_amdgcn_mfma_f32_16x16x32_bf16(b3, a03, ac0, 0, 0, 0);    \
      ac1 = __builtin_amdgcn_mfma_f32_16x16x32_bf16(b3, a13, ac1, 0, 0, 0);    \
      ac2 = __builtin_amdgcn_mfma_f32_16x16x32_bf16(b3, a23, ac2, 0, 0, 0);    \
      ac3 = __builtin_amdgcn_mfma_f32_16x16x32_bf16(b3, a33, ac3, 0, 0, 0);    \
      const unsigned colb = (unsigned)(jt + ct * 16 + lquad * 4);              \
      _Pragma("unroll")                                                        \
      for (int r = 0; r < 4; ++r) {                                            \
        const unsigned cr = colb + r;                                          \
        INSROW(0, packsi(ac0[r], cr));                                         \
        INSROW(1, packsi(ac1[r], cr));                                         \
        INSROW(2, packsi(ac2[r], cr));                                         \
        INSROW(3, packsi(ac3[r], cr));                                         \
      }                                                                        \
    }                                                                          \
  }

#define INS4(G, V) NET4(q##G##0, q##G##1, q##G##2, q##G##3, (V))
#define INS5(G, V) NET5(q##G##0, q##G##1, q##G##2, q##G##3, q##G##4, (V))

  if (hasDiag) {
    KBODY(INS5)
  } else {
    KBODY(INS4)
  }
#undef KBODY

  // Merge across lquads (lanes sharing lrow hold the same 4 rows).
#define MERGE4(G, M)                                                           \
  {                                                                            \
    float o0 = __shfl_xor(q##G##0, M), o1 = __shfl_xor(q##G##1, M),            \
          o2 = __shfl_xor(q##G##2, M), o3 = __shfl_xor(q##G##3, M);            \
    NET4(q##G##0, q##G##1, q##G##2, q##G##3, o0);                              \
    NET4(q##G##0, q##G##1, q##G##2, q##G##3, o1);                              \
    NET4(q##G##0, q##G##1, q##G##2, q##G##3, o2);                              \
    NET4(q##G##0, q##G##1, q##G##2, q##G##3, o3);                              \
  }
#define MERGE5(G, M)                                                           \
  {                                                                            \
    float o0 = __shfl_xor(q##G##0, M), o1 = __shfl_xor(q##G##1, M),            \
          o2 = __shfl_xor(q##G##2, M), o3 = __shfl_xor(q##G##3, M),            \
          o4 = __shfl_xor(q##G##4, M);                                         \
    NET5(q##G##0, q##G##1, q##G##2, q##G##3, q##G##4, o0);                     \
    NET5(q##G##0, q##G##1, q##G##2, q##G##3, q##G##4, o1);                     \
    NET5(q##G##0, q##G##1, q##G##2, q##G##3, q##G##4, o2);                     \
    NET5(q##G##0, q##G##1, q##G##2, q##G##3, q##G##4, o3);                     \
    NET5(q##G##0, q##G##1, q##G##2, q##G##3, q##G##4, o4);                     \
  }
  if (hasDiag) {
    MERGE5(0, 16) MERGE5(1, 16) MERGE5(2, 16) MERGE5(3, 16)
    MERGE5(0, 32) MERGE5(1, 32) MERGE5(2, 32) MERGE5(3, 32)
  } else {
    MERGE4(0, 16) MERGE4(1, 16) MERGE4(2, 16) MERGE4(3, 16)
    MERGE4(0, 32) MERGE4(1, 32) MERGE4(2, 32) MERGE4(3, 32)
  }

  if (lquad == 0) {
    // pscore layout: [row][CH*5] -> coalesced per-row read in final_kernel.
    float* b0p = pscore + (size_t)(r0)*80 + chunk * 5;
    b0p[0] = q00; b0p[1] = q01; b0p[2] = q02; b0p[3] = q03; b0p[4] = q04;
    float* b1p = pscore + (size_t)(r0 + 16) * 80 + chunk * 5;
    b1p[0] = q10; b1p[1] = q11; b1p[2] = q12; b1p[3] = q13; b1p[4] = q14;
    float* b2p = pscore + (size_t)(r0 + 32) * 80 + chunk * 5;
    b2p[0] = q20; b2p[1] = q21; b2p[2] = q22; b2p[3] = q23; b2p[4] = q24;
    float* b3p = pscore + (size_t)(r0 + 48) * 80 + chunk * 5;
    b3p[0] = q30; b3p[1] = q31; b3p[2] = q32; b3p[3] = q33; b3p[4] = q34;
  }
}

// Kernel 3: chunk merge (packed, max networks) -> neg idx -> exact fp32 hinge
// -> 64 bins.
__global__ __launch_bounds__(256) void final_kernel(const float* __restrict__ x,
                                                    const float* __restrict__ pos,
                                                    const float* __restrict__ pscore,
                                                    float* __restrict__ partial) {
  const int wave = threadIdx.x >> 6, lane = threadIdx.x & 63;
  const int row = blockIdx.x * 4 + wave;

  float q0 = PACK_INIT, q1 = PACK_INIT, q2 = PACK_INIT, q3 = PACK_INIT,
        q4 = PACK_INIT;
  if (lane < CH) {
    const float* b = pscore + (size_t)row * 80 + lane * 5;   // contiguous row
    q0 = b[0]; q1 = b[1]; q2 = b[2]; q3 = b[3]; q4 = b[4];
  }
#pragma unroll
  for (int m = 1; m < CH; m <<= 1) {
    float o0 = __shfl_xor(q0, m), o1 = __shfl_xor(q1, m), o2 = __shfl_xor(q2, m),
          o3 = __shfl_xor(q3, m), o4 = __shfl_xor(q4, m);
    NET5(q0, q1, q2, q3, q4, o0);
    NET5(q0, q1, q2, q3, q4, o1);
    NET5(q0, q1, q2, q3, q4, o2);
    NET5(q0, q1, q2, q3, q4, o3);
    NET5(q0, q1, q2, q3, q4, o4);
  }
  const int nidx = (int)(__float_as_uint(__shfl(q4, 0)) & 0x1FFFu);

  const float2 xv  = ((const float2*)(x   + (size_t)row  * DD))[lane];
  const float2 pv  = ((const float2*)(pos + (size_t)row  * DD))[lane];
  const float2 nvv = ((const float2*)(x   + (size_t)nidx * DD))[lane];
  float a0 = xv.x - pv.x + 1e-6f, a1 = xv.y - pv.y + 1e-6f;
  float b0 = xv.x - nvv.x + 1e-6f, b1 = xv.y - nvv.y + 1e-6f;
  float dap = a0 * a0 + a1 * a1;
  float dan = b0 * b0 + b1 * b1;
#pragma unroll
  for (int off = 32; off; off >>= 1) {
    dap += __shfl_down(dap, off);
    dan += __shfl_down(dan, off);
  }
  __shared__ float hs[4];
  if (lane == 0) hs[wave] = fmaxf(sqrtf(dap) - sqrtf(dan) + 0.3f, 0.0f);
  __syncthreads();
  if (threadIdx.x == 0) {
    float s = hs[0] + hs[1] + hs[2] + hs[3];
    atomicAdd(&partial[blockIdx.x & (NPART - 1)], s);
  }
}

// Kernel 4: one wave sums the 64 bins -> mean.
__global__ __launch_bounds__(64) void reduce_kernel(const float* __restrict__ partial,
                                                    float* __restrict__ out) {
  float v = partial[threadIdx.x];
#pragma unroll
  for (int off = 32; off; off >>= 1) v += __shfl_down(v, off);
  if (threadIdx.x == 0) out[0] = v * (1.0f / 8192.0f);
}

extern "C" void kernel_launch(void* const* d_in, const int* in_sizes, int n_in,
                              void* d_out, int out_size, void* d_ws, size_t ws_size,
                              hipStream_t stream) {
  const float* x   = (const float*)d_in[0];
  const float* pos = (const float*)d_in[1];
  float* out = (float*)d_out;

  char* w = (char*)d_ws;
  unsigned short* xb = (unsigned short*)w;                       // 2 MB
  float* sq = (float*)(w + (size_t)NN * DD * 2);                 // 32 KB
  float* pscore = (float*)(w + (size_t)NN * DD * 2 + (size_t)NN * 4);  // 2.62 MB
  float* partial = (float*)(w + (size_t)NN * DD * 2 + (size_t)NN * 4 +
                            (size_t)NN * 80 * 4);                // 256 B

  prep_kernel<<<NN / 4, 256, 0, stream>>>(x, xb, sq, partial);
  dist_topk_kernel<<<dim3(NN / 256, CH), 256, 0, stream>>>(xb, sq, pscore);
  final_kernel<<<NN / 4, 256, 0, stream>>>(x, pos, pscore, partial);
  reduce_kernel<<<1, 64, 0, stream>>>(partial, out);
}